// Round 1
// baseline (147.004 us; speedup 1.0000x reference)
//
#include <hip/hip_runtime.h>

#define S_LEN    1024
#define B_SZ     8
#define D_IN     64
#define D_OUT    96
#define NB       8
#define SPAD     100   // padded row stride (floats) for per-batch LDS buffers
#define WPAD     100   // padded row stride (floats) for W tile
#define NTHREADS 256

// cos(2*pi*s/period) accumulation: W[e] = sum_g P[e*8+g] * cos(2*pi*s/(e*8+g+2))
// Uses v_rcp + v_fract + v_cos (revolutions). For periods < 1024 we do exact
// integer argument reduction (s % per) so accuracy beats the fp32 reference.
__device__ __forceinline__ void compute_W(float* __restrict__ w,
                                          const float* __restrict__ P,
                                          int s, int tid) {
    const float sf = (float)s;
    for (int e = tid; e < D_OUT * D_OUT; e += NTHREADS) {
        float pl[8];
        *(float4*)(&pl[0]) = *(const float4*)(P + e * NB);
        *(float4*)(&pl[4]) = *(const float4*)(P + e * NB + 4);
        float acc = 0.0f;
        const int base = e * NB + 2;
        if (e < 128) {
            // some period <= 1023: exact integer reduction
            #pragma unroll
            for (int g = 0; g < NB; ++g) {
                int per = base + g;
                int r = (s >= per) ? (s % per) : s;
                float v = (float)r * __builtin_amdgcn_rcpf((float)per);
                v -= floorf(v);
                acc = fmaf(pl[g], __builtin_amdgcn_cosf(v), acc);
            }
        } else {
            // all periods > 1023 >= s: s/per < 1 already
            #pragma unroll
            for (int g = 0; g < NB; ++g) {
                int per = base + g;
                float v = sf * __builtin_amdgcn_rcpf((float)per);
                v -= floorf(v);
                acc = fmaf(pl[g], __builtin_amdgcn_cosf(v), acc);
            }
        }
        int i = e / D_OUT;                 // row
        w[e + (WPAD - D_OUT) * i] = acc;   // w[i*WPAD + j]
    }
}

// LayerNorm over 96 features for 8 rows, in place. tid>>5 = row, tid&31 = lane.
__device__ __forceinline__ void block_layernorm(float* __restrict__ buf,
                                                const float* __restrict__ gamma,
                                                const float* __restrict__ beta,
                                                int tid) {
    const int b = tid >> 5;
    const int r = tid & 31;
    float* row = buf + b * SPAD;
    float v0 = row[r], v1 = row[r + 32], v2 = row[r + 64];
    float sum = v0 + v1 + v2;
    float sq  = fmaf(v0, v0, fmaf(v1, v1, v2 * v2));
    #pragma unroll
    for (int off = 16; off > 0; off >>= 1) {
        sum += __shfl_down(sum, off, 32);
        sq  += __shfl_down(sq,  off, 32);
    }
    sum = __shfl(sum, 0, 32);
    sq  = __shfl(sq,  0, 32);
    const float mu  = sum * (1.0f / 96.0f);
    const float var = fmaf(sq, 1.0f / 96.0f, -(mu * mu));
    const float rs  = rsqrtf(var + 1e-5f);
    row[r]      = fmaf((v0 - mu) * rs, gamma[r],      beta[r]);
    row[r + 32] = fmaf((v1 - mu) * rs, gamma[r + 32], beta[r + 32]);
    row[r + 64] = fmaf((v2 - mu) * rs, gamma[r + 64], beta[r + 64]);
}

__global__ void __launch_bounds__(NTHREADS)
hier_fused(const float* __restrict__ seq,  const float* __restrict__ M1,
           const float* __restrict__ P1,   const float* __restrict__ Wres1,
           const float* __restrict__ g1,   const float* __restrict__ b1,
           const float* __restrict__ M2,   const float* __restrict__ P2,
           const float* __restrict__ g2,   const float* __restrict__ b2,
           float* __restrict__ out) {
    // LDS: 38400 + 3*3200 = 48000 B -> 3 blocks/CU
    __shared__ __align__(16) float w[D_OUT * WPAD];
    __shared__ __align__(16) float xin[B_SZ * SPAD];
    __shared__ __align__(16) float xn[B_SZ * SPAD];
    __shared__ __align__(16) float x1b[B_SZ * SPAD];

    const int s   = blockIdx.x;
    const int tid = threadIdx.x;

    // Load the 8 input rows for this s (8 x 64 floats)
    for (int idx = tid; idx < B_SZ * D_IN; idx += NTHREADS) {
        int b = idx >> 6, k = idx & (D_IN - 1);
        xin[b * SPAD + k] = seq[(b * S_LEN + s) * D_IN + k];
    }
    compute_W(w, P1, s, tid);   // W1[s] -> LDS
    __syncthreads();

    // ---- Layer 1: xt1 = x @ M1^T, residual = x @ Wres1^T ----
    // idx = i*8 + b: 8 distinct matrix rows per wave (cache reuse),
    // 8 distinct b rows at stride 100 -> conflict-free LDS.
    for (int idx = tid; idx < B_SZ * D_OUT; idx += NTHREADS) {
        int i = idx >> 3, b = idx & 7;
        const float4* m  = (const float4*)(M1 + i * D_IN);
        const float4* wr = (const float4*)(Wres1 + i * D_IN);
        const float*  xr = xin + b * SPAD;
        float at = 0.0f, ar = 0.0f;
        #pragma unroll
        for (int k = 0; k < D_IN / 4; ++k) {
            float4 mv = m[k], rv = wr[k];
            float x0 = xr[4*k], x1 = xr[4*k+1], x2 = xr[4*k+2], x3 = xr[4*k+3];
            at = fmaf(mv.x, x0, fmaf(mv.y, x1, fmaf(mv.z, x2, fmaf(mv.w, x3, at))));
            ar = fmaf(rv.x, x0, fmaf(rv.y, x1, fmaf(rv.z, x2, fmaf(rv.w, x3, ar))));
        }
        xn[b * SPAD + i]  = at;  // pre-norm xt1
        x1b[b * SPAD + i] = ar;  // residual
    }
    __syncthreads();

    block_layernorm(xn, g1, b1, tid);
    __syncthreads();

    // Nk1 + residual -> x1b
    for (int idx = tid; idx < B_SZ * D_OUT; idx += NTHREADS) {
        int i = idx >> 3, b = idx & 7;
        const float* wrow = w + i * WPAD;
        const float* xr   = xn + b * SPAD;
        float acc = 0.0f;
        #pragma unroll
        for (int j = 0; j < D_OUT / 4; ++j) {
            float4 wv = *(const float4*)(wrow + 4 * j);
            float4 xv = *(const float4*)(xr + 4 * j);
            acc = fmaf(wv.x, xv.x, fmaf(wv.y, xv.y, fmaf(wv.z, xv.z, fmaf(wv.w, xv.w, acc))));
        }
        x1b[b * SPAD + i] += acc;
    }
    __syncthreads();  // all reads of W1 and writes of x1b complete

    compute_W(w, P2, s, tid);   // W2[s] -> LDS (overwrite)

    // ---- Layer 2: xt2 = x1 @ M2^T ----
    for (int idx = tid; idx < B_SZ * D_OUT; idx += NTHREADS) {
        int i = idx >> 3, b = idx & 7;
        const float4* m  = (const float4*)(M2 + i * D_OUT);
        const float*  xr = x1b + b * SPAD;
        float at = 0.0f;
        #pragma unroll
        for (int k = 0; k < D_OUT / 4; ++k) {
            float4 mv = m[k];
            at = fmaf(mv.x, xr[4*k], fmaf(mv.y, xr[4*k+1],
                 fmaf(mv.z, xr[4*k+2], fmaf(mv.w, xr[4*k+3], at))));
        }
        xn[b * SPAD + i] = at;
    }
    __syncthreads();

    block_layernorm(xn, g2, b2, tid);
    __syncthreads();

    // Nk2 + identity residual -> out
    for (int idx = tid; idx < B_SZ * D_OUT; idx += NTHREADS) {
        int i = idx >> 3, b = idx & 7;
        const float* wrow = w + i * WPAD;
        const float* xr   = xn + b * SPAD;
        float acc = 0.0f;
        #pragma unroll
        for (int j = 0; j < D_OUT / 4; ++j) {
            float4 wv = *(const float4*)(wrow + 4 * j);
            float4 xv = *(const float4*)(xr + 4 * j);
            acc = fmaf(wv.x, xv.x, fmaf(wv.y, xv.y, fmaf(wv.z, xv.z, fmaf(wv.w, xv.w, acc))));
        }
        out[(b * S_LEN + s) * D_OUT + i] = acc + x1b[b * SPAD + i];
    }
}

extern "C" void kernel_launch(void* const* d_in, const int* in_sizes, int n_in,
                              void* d_out, int out_size, void* d_ws, size_t ws_size,
                              hipStream_t stream) {
    const float* seq   = (const float*)d_in[0];
    const float* M1    = (const float*)d_in[1];
    const float* P1    = (const float*)d_in[2];
    const float* Wres1 = (const float*)d_in[3];
    const float* g1    = (const float*)d_in[4];
    const float* b1    = (const float*)d_in[5];
    const float* M2    = (const float*)d_in[6];
    const float* P2    = (const float*)d_in[7];
    const float* g2    = (const float*)d_in[8];
    const float* b2    = (const float*)d_in[9];
    float* out = (float*)d_out;

    hier_fused<<<dim3(S_LEN), dim3(NTHREADS), 0, stream>>>(
        seq, M1, P1, Wres1, g1, b1, M2, P2, g2, b2, out);
}